// Round 7
// baseline (436.449 us; speedup 1.0000x reference)
//
#include <hip/hip_runtime.h>
#include <hip/hip_fp16.h>

#define HH 256
#define WW 256
#define NB 64
#define NPIX (NB * HH * WW)      // 4,194,304 pixels
#define NF4  (NPIX / 4)
#define ROW4 (WW / 4)
#define EPSF 1e-12f
#define NTHR 256
#define NBLK (NF4 / NTHR)

// D-kernel tile geometry
#define TW 64
#define TH 32
#define DTILES (NB * (HH / TH) * (WW / TW))   // 64*8*4 = 2048

__device__ __forceinline__ float4 ld4(const float* p, int f) {
    return ((const float4*)p)[f];
}
__device__ __forceinline__ void st4(float* p, int f, const float* v) {
    ((float4*)p)[f] = make_float4(v[0], v[1], v[2], v[3]);
}
__device__ __forceinline__ void ld4h(const __half* p, int f, float* o) {
    float2 raw = ((const float2*)p)[f];
    __half2 h0 = *(__half2*)&raw.x;
    __half2 h1 = *(__half2*)&raw.y;
    float2 a = __half22float2(h0), b = __half22float2(h1);
    o[0] = a.x; o[1] = a.y; o[2] = b.x; o[3] = b.y;
}
__device__ __forceinline__ void st4h(__half* p, int f, const float* v) {
    __half2 h0 = __floats2half2_rn(v[0], v[1]);
    __half2 h1 = __floats2half2_rn(v[2], v[3]);
    float2 raw;
    raw.x = *(float*)&h0; raw.y = *(float*)&h1;
    ((float2*)p)[f] = raw;
}

__device__ __forceinline__ void thresh(
    float gx, float gy, float rho, float grad, float l_t,
    float& v1, float& v2)
{
    float th = l_t * grad;
    if (rho < -th)      { v1 =  l_t * gx; v2 =  l_t * gy; }
    else if (rho > th)  { v1 = -l_t * gx; v2 = -l_t * gy; }
    else                { float s = -rho / grad; v1 = s * gx; v2 = s * gy; }
}

__device__ __forceinline__ void pupd(
    float pao, float pbo, float ux, float uy, float taut,
    float& pa, float& pb)
{
    float n = sqrtf(ux * ux + uy * uy + EPSF);
    float r = 1.f / (1.f + taut * n);
    pa = (pao + taut * ux) * r;
    pb = (pbo + taut * uy) * r;
}

// ---------------------------------------------------------------------------
// S: g2x/g2y (fp16) + rc (fp32) from x,y; iteration-0 u-update (u = v).
// ---------------------------------------------------------------------------
__global__ __launch_bounds__(NTHR) void s_kernel(
    const float* __restrict__ x, const float* __restrict__ y,
    __half* __restrict__ g2x, __half* __restrict__ g2y, float* __restrict__ rc,
    float* __restrict__ u1, float* __restrict__ u2,
    const float* __restrict__ tp, const float* __restrict__ lp)
{
    int f = blockIdx.x * NTHR + threadIdx.x;
    const float l_t = lp[0] * tp[0];

    int idx = f << 2;
    int i  = (idx >> 8) & 255;
    int j0 = idx & 255;

    float4 xc4 = ld4(x, f), yc4 = ld4(y, f);
    const float* xc = (const float*)&xc4;
    const float* yc = (const float*)&yc4;

    float4 a4, b4;
    if (i == 0)            { a4 = ld4(x, f + ROW4); b4 = xc4; }
    else if (i == HH - 1)  { a4 = xc4; b4 = ld4(x, f - ROW4); }
    else                   { a4 = ld4(y, f + ROW4); b4 = ld4(y, f - ROW4); }
    const float* aa = (const float*)&a4;
    const float* bb = (const float*)&b4;

    float yl = (j0 > 0)      ? y[idx - 1] : 0.f;
    float yr = (j0 < WW - 4) ? y[idx + 4] : 0.f;

    float gxo[4], gyo[4], rco[4], u1o[4], u2o[4];
    #pragma unroll
    for (int k = 0; k < 4; ++k) {
        int j = j0 + k;
        float gx;
        if (j == 0)            gx = 0.5f * (xc[1] - xc[0]);
        else if (j == WW - 1)  gx = 0.5f * (xc[3] - xc[2]);
        else {
            float ynext = (k < 3) ? yc[k + 1] : yr;
            float yprev = (k > 0) ? yc[k - 1] : yl;
            gx = 0.5f * (ynext - yprev);
        }
        float gy = 0.5f * (aa[k] - bb[k]);
        gx = __half2float(__float2half_rn(gx));
        gy = __half2float(__float2half_rn(gy));
        float rcv = yc[k] - xc[k];
        float grad = gx * gx + gy * gy + EPSF;
        float rho  = rcv + EPSF;
        float v1, v2;
        thresh(gx, gy, rho, grad, l_t, v1, v2);
        gxo[k] = gx; gyo[k] = gy; rco[k] = rcv;
        u1o[k] = v1; u2o[k] = v2;
    }
    st4h(g2x, f, gxo); st4h(g2y, f, gyo); st4(rc, f, rco);
    st4(u1, f, u1o);   st4(u2, f, u2o);
}

// ---------------------------------------------------------------------------
// D: two fused (p-update, u-update) steps on a 32x64 tile via LDS staging.
//   P0: p_a over [-2,33)x[-2,65) from (p_in, u_in) -> LDS fp16
//   P1: u_a over [-1,33)x[-1,65) from (g, rc, u_in, p_a) -> LDS fp32
//   P2: p_b over [-1,32)x[-1,64) from (p_a, u_a), in-place in LDS
//   P3: u_b interior + store u_b, p_b
// P0T: p_in == 0 (first D kernel).
// ---------------------------------------------------------------------------
template <bool P0T>
__global__ __launch_bounds__(NTHR) void d_kernel(
    const __half* __restrict__ g2x, const __half* __restrict__ g2y,
    const float* __restrict__ rc,
    const float* __restrict__ u1i, const float* __restrict__ u2i,
    const __half* __restrict__ p11i, const __half* __restrict__ p12i,
    const __half* __restrict__ p21i, const __half* __restrict__ p22i,
    float* __restrict__ u1o, float* __restrict__ u2o,
    __half* __restrict__ p11o, __half* __restrict__ p12o,
    __half* __restrict__ p21o, __half* __restrict__ p22o,
    const float* __restrict__ tp, const float* __restrict__ lp,
    const float* __restrict__ ap)
{
    __shared__ __half ps[4][35][68];   // p fields, rows -2..32, cols -2..65
    __shared__ float  us[2][34][68];   // u fields, rows -1..32, cols -1..65

    const float ts   = tp[0];
    const float l_t  = lp[0] * ts;
    const float taut = ap[0] / ts;

    const int tile = blockIdx.x;
    const int j0t  = (tile & 3) * TW;
    const int i0t  = ((tile >> 2) & 7) * TH;
    const int base = (tile >> 5) * (HH * WW);

    // ---- Phase 0: p_a -> LDS ----
    for (int q = threadIdx.x; q < 35 * 67; q += NTHR) {
        int r = q / 67 - 2;            // -2..32
        int c = q % 67 - 2;            // -2..64
        int gi = i0t + r, gj = j0t + c;
        float o11 = 0.f, o12 = 0.f, o21 = 0.f, o22 = 0.f;
        if (gi >= 0 && gi < HH && gj >= 0 && gj < WW) {
            int idx = base + gi * WW + gj;
            float u1c = u1i[idx], u2c = u2i[idx];
            bool hR = (gj < WW - 1), hD = (gi < HH - 1);
            float u1x = hR ? u1i[idx + 1]  - u1c : 0.f;
            float u2x = hR ? u2i[idx + 1]  - u2c : 0.f;
            float u1y = hD ? u1i[idx + WW] - u1c : 0.f;
            float u2y = hD ? u2i[idx + WW] - u2c : 0.f;
            float c11 = 0.f, c12 = 0.f, c21 = 0.f, c22 = 0.f;
            if (!P0T) {
                c11 = __half2float(p11i[idx]);
                c12 = __half2float(p12i[idx]);
                c21 = __half2float(p21i[idx]);
                c22 = __half2float(p22i[idx]);
            }
            pupd(c11, c12, u1x, u1y, taut, o11, o12);
            pupd(c21, c22, u2x, u2y, taut, o21, o22);
        }
        ps[0][r + 2][c + 2] = __float2half_rn(o11);
        ps[1][r + 2][c + 2] = __float2half_rn(o12);
        ps[2][r + 2][c + 2] = __float2half_rn(o21);
        ps[3][r + 2][c + 2] = __float2half_rn(o22);
    }
    __syncthreads();

    // ---- Phase 1: u_a -> LDS ----
    for (int q = threadIdx.x; q < 34 * 66; q += NTHR) {
        int r = q / 66 - 1;            // -1..32
        int c = q % 66 - 1;            // -1..64
        int gi = i0t + r, gj = j0t + c;
        float u1v = 0.f, u2v = 0.f;
        if (gi >= 0 && gi < HH && gj >= 0 && gj < WW) {
            int idx = base + gi * WW + gj;
            float gx  = __half2float(g2x[idx]);
            float gy  = __half2float(g2y[idx]);
            float rcv = rc[idx];
            float u1c = u1i[idx], u2c = u2i[idx];
            int rr = r + 2, cc = c + 2;
            float t11 = (gj < WW-1) ? __half2float(ps[0][rr][cc])   : 0.f;
            float l11 = (gj > 0)    ? __half2float(ps[0][rr][cc-1]) : 0.f;
            float t12 = (gi < HH-1) ? __half2float(ps[1][rr][cc])   : 0.f;
            float l12 = (gi > 0)    ? __half2float(ps[1][rr-1][cc]) : 0.f;
            float t21 = (gj < WW-1) ? __half2float(ps[2][rr][cc])   : 0.f;
            float l21 = (gj > 0)    ? __half2float(ps[2][rr][cc-1]) : 0.f;
            float t22 = (gi < HH-1) ? __half2float(ps[3][rr][cc])   : 0.f;
            float l22 = (gi > 0)    ? __half2float(ps[3][rr-1][cc]) : 0.f;
            float div1 = (t11 - l11) + (t12 - l12);
            float div2 = (t21 - l21) + (t22 - l22);
            float grad = gx * gx + gy * gy + EPSF;
            float rho  = rcv + gx * u1c + gy * u2c + EPSF;
            float v1, v2;
            thresh(gx, gy, rho, grad, l_t, v1, v2);
            u1v = v1 + u1c + ts * div1;
            u2v = v2 + u2c + ts * div2;
        }
        us[0][r + 1][c + 2] = u1v;
        us[1][r + 1][c + 2] = u2v;
    }
    __syncthreads();

    // ---- Phase 2: p_b, in-place over p_a ----
    for (int q = threadIdx.x; q < 33 * 65; q += NTHR) {
        int r = q / 65 - 1;            // -1..31
        int c = q % 65 - 1;            // -1..63
        int gi = i0t + r, gj = j0t + c;
        int rr = r + 1, cc = c + 2;
        float u1c = us[0][rr][cc], u2c = us[1][rr][cc];
        bool hR = (gj < WW - 1), hD = (gi < HH - 1);
        float u1x = hR ? us[0][rr][cc + 1] - u1c : 0.f;
        float u2x = hR ? us[1][rr][cc + 1] - u2c : 0.f;
        float u1y = hD ? us[0][rr + 1][cc] - u1c : 0.f;
        float u2y = hD ? us[1][rr + 1][cc] - u2c : 0.f;
        float c11 = __half2float(ps[0][r + 2][c + 2]);
        float c12 = __half2float(ps[1][r + 2][c + 2]);
        float c21 = __half2float(ps[2][r + 2][c + 2]);
        float c22 = __half2float(ps[3][r + 2][c + 2]);
        float o11, o12, o21, o22;
        pupd(c11, c12, u1x, u1y, taut, o11, o12);
        pupd(c21, c22, u2x, u2y, taut, o21, o22);
        ps[0][r + 2][c + 2] = __float2half_rn(o11);
        ps[1][r + 2][c + 2] = __float2half_rn(o12);
        ps[2][r + 2][c + 2] = __float2half_rn(o21);
        ps[3][r + 2][c + 2] = __float2half_rn(o22);
    }
    __syncthreads();

    // ---- Phase 3: u_b interior; store u_b (fp32) and p_b (fp16) ----
    for (int q = threadIdx.x; q < TH * TW; q += NTHR) {
        int r = q >> 6, c = q & 63;
        int gi = i0t + r, gj = j0t + c;
        int idx = base + gi * WW + gj;
        int rr = r + 1, cc = c + 2;
        float u1c = us[0][rr][cc], u2c = us[1][rr][cc];
        float gx  = __half2float(g2x[idx]);
        float gy  = __half2float(g2y[idx]);
        float rcv = rc[idx];

        __half h11 = ps[0][r + 2][cc], h12 = ps[1][r + 2][cc];
        __half h21 = ps[2][r + 2][cc], h22 = ps[3][r + 2][cc];
        float t11 = (gj < WW-1) ? __half2float(h11) : 0.f;
        float l11 = (gj > 0)    ? __half2float(ps[0][r + 2][cc - 1]) : 0.f;
        float t12 = (gi < HH-1) ? __half2float(h12) : 0.f;
        float l12 = (gi > 0)    ? __half2float(ps[1][r + 1][cc]) : 0.f;
        float t21 = (gj < WW-1) ? __half2float(h21) : 0.f;
        float l21 = (gj > 0)    ? __half2float(ps[2][r + 2][cc - 1]) : 0.f;
        float t22 = (gi < HH-1) ? __half2float(h22) : 0.f;
        float l22 = (gi > 0)    ? __half2float(ps[3][r + 1][cc]) : 0.f;
        float div1 = (t11 - l11) + (t12 - l12);
        float div2 = (t21 - l21) + (t22 - l22);

        float grad = gx * gx + gy * gy + EPSF;
        float rho  = rcv + gx * u1c + gy * u2c + EPSF;
        float v1, v2;
        thresh(gx, gy, rho, grad, l_t, v1, v2);
        u1o[idx] = v1 + u1c + ts * div1;
        u2o[idx] = v2 + u2c + ts * div2;
        p11o[idx] = h11; p12o[idx] = h12;
        p21o[idx] = h21; p22o[idx] = h22;
    }
}

// ---------------------------------------------------------------------------
// F: single fused p-update + u-update (gather style), used for the last step.
// LAST: skip p stores; u_out is the final output.
// ---------------------------------------------------------------------------
template <bool P0, bool LAST>
__global__ __launch_bounds__(NTHR) void f_kernel(
    const __half* __restrict__ g2x, const __half* __restrict__ g2y,
    const float* __restrict__ rc,
    const float* __restrict__ u1i, const float* __restrict__ u2i,
    const __half* __restrict__ p11i, const __half* __restrict__ p12i,
    const __half* __restrict__ p21i, const __half* __restrict__ p22i,
    float* __restrict__ u1o, float* __restrict__ u2o,
    __half* __restrict__ p11o, __half* __restrict__ p12o,
    __half* __restrict__ p21o, __half* __restrict__ p22o,
    const float* __restrict__ tp, const float* __restrict__ lp,
    const float* __restrict__ ap)
{
    int f = blockIdx.x * NTHR + threadIdx.x;
    const float ts   = tp[0];
    const float l_t  = lp[0] * ts;
    const float taut = ap[0] / ts;

    int idx = f << 2;
    int i  = (idx >> 8) & 255;
    int j0 = idx & 255;
    bool hasUp = (i > 0), hasDn = (i < HH - 1);
    bool hasL  = (j0 > 0), hasR = (j0 < WW - 4);

    float4 z4 = make_float4(0.f, 0.f, 0.f, 0.f);

    float4 u1c4 = ld4(u1i, f),                     u2c4 = ld4(u2i, f);
    float4 u1u4 = hasUp ? ld4(u1i, f - ROW4) : z4, u2u4 = hasUp ? ld4(u2i, f - ROW4) : z4;
    float4 u1d4 = hasDn ? ld4(u1i, f + ROW4) : z4, u2d4 = hasDn ? ld4(u2i, f + ROW4) : z4;
    float u1l  = hasL ? u1i[idx - 1] : 0.f,  u2l  = hasL ? u2i[idx - 1] : 0.f;
    float u1r  = hasR ? u1i[idx + 4] : 0.f,  u2r  = hasR ? u2i[idx + 4] : 0.f;
    float u1ur = (hasUp && hasR) ? u1i[idx - WW + 4] : 0.f;
    float u2ur = (hasUp && hasR) ? u2i[idx - WW + 4] : 0.f;
    float u1dl = (hasDn && hasL) ? u1i[idx + WW - 1] : 0.f;
    float u2dl = (hasDn && hasL) ? u2i[idx + WW - 1] : 0.f;

    const float* u1c = (const float*)&u1c4;
    const float* u2c = (const float*)&u2c4;
    const float* u1u = (const float*)&u1u4;
    const float* u2u = (const float*)&u2u4;
    const float* u1d = (const float*)&u1d4;
    const float* u2d = (const float*)&u2d4;

    float c11[4], c12[4], c21[4], c22[4];
    float p12uo[4], p22uo[4];
    float p11lo = 0.f, p21lo = 0.f;
    if (!P0) {
        ld4h(p11i, f, c11); ld4h(p12i, f, c12);
        ld4h(p21i, f, c21); ld4h(p22i, f, c22);
        if (hasUp) { ld4h(p12i, f - ROW4, p12uo); ld4h(p22i, f - ROW4, p22uo); }
        else { p12uo[0]=p12uo[1]=p12uo[2]=p12uo[3]=0.f;
               p22uo[0]=p22uo[1]=p22uo[2]=p22uo[3]=0.f; }
        if (hasL) { p11lo = __half2float(p11i[idx - 1]);
                    p21lo = __half2float(p21i[idx - 1]); }
    } else {
        #pragma unroll
        for (int k = 0; k < 4; ++k) {
            c11[k]=c12[k]=c21[k]=c22[k]=0.f; p12uo[k]=p22uo[k]=0.f;
        }
    }

    float p11n[4], p12n[4], p21n[4], p22n[4];
    #pragma unroll
    for (int k = 0; k < 4; ++k) {
        int j = j0 + k;
        float u1x = (j < WW-1) ? ((k < 3) ? u1c[k+1] : u1r) - u1c[k] : 0.f;
        float u2x = (j < WW-1) ? ((k < 3) ? u2c[k+1] : u2r) - u2c[k] : 0.f;
        float u1y = hasDn ? u1d[k] - u1c[k] : 0.f;
        float u2y = hasDn ? u2d[k] - u2c[k] : 0.f;
        pupd(c11[k], c12[k], u1x, u1y, taut, p11n[k], p12n[k]);
        pupd(c21[k], c22[k], u2x, u2y, taut, p21n[k], p22n[k]);
    }

    float p11nl = 0.f, p21nl = 0.f;
    if (hasL) {
        float u1x = u1c[0] - u1l;
        float u2x = u2c[0] - u2l;
        float u1y = hasDn ? u1dl - u1l : 0.f;
        float u2y = hasDn ? u2dl - u2l : 0.f;
        float d0, d1;
        pupd(p11lo, 0.f, u1x, u1y, taut, p11nl, d0);
        pupd(p21lo, 0.f, u2x, u2y, taut, p21nl, d1);
    }

    float p12nu[4] = {0.f,0.f,0.f,0.f}, p22nu[4] = {0.f,0.f,0.f,0.f};
    if (hasUp) {
        #pragma unroll
        for (int k = 0; k < 4; ++k) {
            int j = j0 + k;
            float u1x = (j < WW-1) ? ((k < 3) ? u1u[k+1] : u1ur) - u1u[k] : 0.f;
            float u2x = (j < WW-1) ? ((k < 3) ? u2u[k+1] : u2ur) - u2u[k] : 0.f;
            float u1y = u1c[k] - u1u[k];
            float u2y = u2c[k] - u2u[k];
            float d0, d1;
            pupd(0.f, p12uo[k], u1x, u1y, taut, d0, p12nu[k]);
            pupd(0.f, p22uo[k], u2x, u2y, taut, d1, p22nu[k]);
        }
    }

    float gx[4], gy[4];
    ld4h(g2x, f, gx); ld4h(g2y, f, gy);
    float4 rc4 = ld4(rc, f);
    const float* rcv = (const float*)&rc4;

    float u1n[4], u2n[4];
    #pragma unroll
    for (int k = 0; k < 4; ++k) {
        int j = j0 + k;
        float t11 = (j < WW-1) ? p11n[k] : 0.f;
        float l11 = (k == 0) ? p11nl : p11n[k-1];
        float t21 = (j < WW-1) ? p21n[k] : 0.f;
        float l21 = (k == 0) ? p21nl : p21n[k-1];
        float t12 = hasDn ? p12n[k] : 0.f;
        float t22 = hasDn ? p22n[k] : 0.f;
        float div1 = (t11 - l11) + (t12 - p12nu[k]);
        float div2 = (t21 - l21) + (t22 - p22nu[k]);

        float grad = gx[k]*gx[k] + gy[k]*gy[k] + EPSF;
        float rho  = rcv[k] + gx[k]*u1c[k] + gy[k]*u2c[k] + EPSF;
        float v1, v2;
        thresh(gx[k], gy[k], rho, grad, l_t, v1, v2);
        u1n[k] = v1 + u1c[k] + ts * div1;
        u2n[k] = v2 + u2c[k] + ts * div2;
    }

    st4(u1o, f, u1n); st4(u2o, f, u2n);
    if (!LAST) {
        st4h(p11o, f, p11n); st4h(p12o, f, p12n);
        st4h(p21o, f, p21n); st4h(p22o, f, p22n);
    }
}

// ---------------------------------------------------------------------------
extern "C" void kernel_launch(void* const* d_in, const int* in_sizes, int n_in,
                              void* d_out, int out_size, void* d_ws, size_t ws_size,
                              hipStream_t stream) {
    const float* x = (const float*)d_in[0];
    const float* y = (const float*)d_in[1];
    const float* t = (const float*)d_in[8];
    const float* l = (const float*)d_in[9];
    const float* a = (const float*)d_in[10];

    float* u1out = (float*)d_out;
    float* u2out = u1out + NPIX;

    char* ws = (char*)d_ws;
    float*  rcp_ = (float*)ws;                               ws += (size_t)NPIX * 4;
    float*  u1A  = (float*)ws;                               ws += (size_t)NPIX * 4;
    float*  u2A  = (float*)ws;                               ws += (size_t)NPIX * 4;
    float*  u1B  = (float*)ws;                               ws += (size_t)NPIX * 4;
    float*  u2B  = (float*)ws;                               ws += (size_t)NPIX * 4;
    __half* g2x  = (__half*)ws;                              ws += (size_t)NPIX * 2;
    __half* g2y  = (__half*)ws;                              ws += (size_t)NPIX * 2;
    __half* p11A = (__half*)ws;                              ws += (size_t)NPIX * 2;
    __half* p12A = (__half*)ws;                              ws += (size_t)NPIX * 2;
    __half* p21A = (__half*)ws;                              ws += (size_t)NPIX * 2;
    __half* p22A = (__half*)ws;                              ws += (size_t)NPIX * 2;
    __half* p11B = (__half*)ws;                              ws += (size_t)NPIX * 2;
    __half* p12B = (__half*)ws;                              ws += (size_t)NPIX * 2;
    __half* p21B = (__half*)ws;                              ws += (size_t)NPIX * 2;
    __half* p22B = (__half*)ws;

    dim3 block(NTHR);

    // S: U0 -> uA
    s_kernel<<<dim3(NBLK), block, 0, stream>>>(x, y, g2x, g2y, rcp_,
                                               u1A, u2A, t, l);
    // D1: [P0 U1 P1 U2]  u: A->B, p: ->B
    d_kernel<true><<<dim3(DTILES), block, 0, stream>>>(
        g2x, g2y, rcp_, u1A, u2A, p11A, p12A, p21A, p22A,
        u1B, u2B, p11B, p12B, p21B, p22B, t, l, a);
    // D2: [P2 U3 P3 U4]  u: B->A, p: B->A
    d_kernel<false><<<dim3(DTILES), block, 0, stream>>>(
        g2x, g2y, rcp_, u1B, u2B, p11B, p12B, p21B, p22B,
        u1A, u2A, p11A, p12A, p21A, p22A, t, l, a);
    // D3: [P4 U5 P5 U6]  u: A->B, p: A->B
    d_kernel<false><<<dim3(DTILES), block, 0, stream>>>(
        g2x, g2y, rcp_, u1A, u2A, p11A, p12A, p21A, p22A,
        u1B, u2B, p11B, p12B, p21B, p22B, t, l, a);
    // D4: [P6 U7 P7 U8]  u: B->A, p: B->A
    d_kernel<false><<<dim3(DTILES), block, 0, stream>>>(
        g2x, g2y, rcp_, u1B, u2B, p11B, p12B, p21B, p22B,
        u1A, u2A, p11A, p12A, p21A, p22A, t, l, a);
    // F_last: [P8 U9] -> d_out (p store dead)
    f_kernel<false, true><<<dim3(NBLK), block, 0, stream>>>(
        g2x, g2y, rcp_, u1A, u2A, p11A, p12A, p21A, p22A,
        u1out, u2out, p11B, p12B, p21B, p22B, t, l, a);
}

// Round 8
// 426.163 us; speedup vs baseline: 1.0241x; 1.0241x over previous
//
#include <hip/hip_runtime.h>
#include <hip/hip_fp16.h>

#define HH 256
#define WW 256
#define NB 64
#define NPIX (NB * HH * WW)      // 4,194,304 pixels
#define NF4  (NPIX / 4)          // 1,048,576 groups of 4
#define ROW4 (WW / 4)            // 64 groups per image row
#define EPSF 1e-12f
#define NTHR 256
#define NBLK (NF4 / NTHR)        // 4096 blocks

__device__ __forceinline__ float4 ld4(const float* p, int f) {
    return ((const float4*)p)[f];
}
__device__ __forceinline__ void st4(float* p, int f, const float* v) {
    ((float4*)p)[f] = make_float4(v[0], v[1], v[2], v[3]);
}
__device__ __forceinline__ void ld4h(const __half* p, int f, float* o) {
    float2 raw = ((const float2*)p)[f];
    __half2 h0 = *(__half2*)&raw.x;
    __half2 h1 = *(__half2*)&raw.y;
    float2 a = __half22float2(h0), b = __half22float2(h1);
    o[0] = a.x; o[1] = a.y; o[2] = b.x; o[3] = b.y;
}
__device__ __forceinline__ void st4h(__half* p, int f, const float* v) {
    __half2 h0 = __floats2half2_rn(v[0], v[1]);
    __half2 h1 = __floats2half2_rn(v[2], v[3]);
    float2 raw;
    raw.x = *(float*)&h0; raw.y = *(float*)&h1;
    ((float2*)p)[f] = raw;
}

// TV-L1 thresholding step.
__device__ __forceinline__ void thresh(
    float gx, float gy, float rho, float grad, float l_t,
    float& v1, float& v2)
{
    float th = l_t * grad;
    if (rho < -th)      { v1 =  l_t * gx; v2 =  l_t * gy; }
    else if (rho > th)  { v1 = -l_t * gx; v2 = -l_t * gy; }
    else                { float s = -rho / grad; v1 = s * gx; v2 = s * gy; }
}

// p-pair update at one pixel for one flow.
__device__ __forceinline__ void pupd(
    float pao, float pbo, float ux, float uy, float taut,
    float& pa, float& pb)
{
    float n = sqrtf(ux * ux + uy * uy + EPSF);
    float r = 1.f / (1.f + taut * n);
    pa = (pao + taut * ux) * r;
    pb = (pbo + taut * uy) * r;
}

// ---------------------------------------------------------------------------
// S: g2x/g2y (fp16) + rc (fp32) from x,y; iteration-0 u-update (u = v, fp16).
// ---------------------------------------------------------------------------
__global__ __launch_bounds__(NTHR) void s_kernel(
    const float* __restrict__ x, const float* __restrict__ y,
    __half* __restrict__ g2x, __half* __restrict__ g2y, float* __restrict__ rc,
    __half* __restrict__ u1, __half* __restrict__ u2,
    const float* __restrict__ tp, const float* __restrict__ lp)
{
    int f = blockIdx.x * NTHR + threadIdx.x;
    const float l_t = lp[0] * tp[0];

    int idx = f << 2;
    int i  = (idx >> 8) & 255;
    int j0 = idx & 255;

    float4 xc4 = ld4(x, f), yc4 = ld4(y, f);
    const float* xc = (const float*)&xc4;
    const float* yc = (const float*)&yc4;

    float4 a4, b4;                       // wave-uniform row branch
    if (i == 0)            { a4 = ld4(x, f + ROW4); b4 = xc4; }
    else if (i == HH - 1)  { a4 = xc4; b4 = ld4(x, f - ROW4); }
    else                   { a4 = ld4(y, f + ROW4); b4 = ld4(y, f - ROW4); }
    const float* aa = (const float*)&a4;
    const float* bb = (const float*)&b4;

    float yl = (j0 > 0)      ? y[idx - 1] : 0.f;
    float yr = (j0 < WW - 4) ? y[idx + 4] : 0.f;

    float gxo[4], gyo[4], rco[4], u1o[4], u2o[4];
    #pragma unroll
    for (int k = 0; k < 4; ++k) {
        int j = j0 + k;
        float gx;
        if (j == 0)            gx = 0.5f * (xc[1] - xc[0]);
        else if (j == WW - 1)  gx = 0.5f * (xc[3] - xc[2]);
        else {
            float ynext = (k < 3) ? yc[k + 1] : yr;
            float yprev = (k > 0) ? yc[k - 1] : yl;
            gx = 0.5f * (ynext - yprev);
        }
        float gy = 0.5f * (aa[k] - bb[k]);
        // quantize g to fp16 NOW so iteration 0 matches iterations 1..9
        gx = __half2float(__float2half_rn(gx));
        gy = __half2float(__float2half_rn(gy));
        float rcv = yc[k] - xc[k];
        float grad = gx * gx + gy * gy + EPSF;
        float rho  = rcv + EPSF;
        float v1, v2;
        thresh(gx, gy, rho, grad, l_t, v1, v2);
        gxo[k] = gx; gyo[k] = gy; rco[k] = rcv;
        u1o[k] = v1; u2o[k] = v2;
    }
    st4h(g2x, f, gxo); st4h(g2y, f, gyo); st4(rc, f, rco);
    st4h(u1, f, u1o);  st4h(u2, f, u2o);
}

// ---------------------------------------------------------------------------
// F: fused p-update(it) + u-update(it+1). Pure gather, no LDS, no barriers.
// u and p state both fp16, both ping-pong. Halo p_new values recomputed
// from u_old. P0: p_old == 0. LAST: skip p stores, write u as fp32 to d_out.
// ---------------------------------------------------------------------------
template <bool P0, bool LAST>
__global__ __launch_bounds__(NTHR) void f_kernel(
    const __half* __restrict__ g2x, const __half* __restrict__ g2y,
    const float* __restrict__ rc,
    const __half* __restrict__ u1i, const __half* __restrict__ u2i,
    const __half* __restrict__ p11i, const __half* __restrict__ p12i,
    const __half* __restrict__ p21i, const __half* __restrict__ p22i,
    __half* __restrict__ u1o, __half* __restrict__ u2o,
    float* __restrict__ u1f, float* __restrict__ u2f,
    __half* __restrict__ p11o, __half* __restrict__ p12o,
    __half* __restrict__ p21o, __half* __restrict__ p22o,
    const float* __restrict__ tp, const float* __restrict__ lp,
    const float* __restrict__ ap)
{
    int f = blockIdx.x * NTHR + threadIdx.x;
    const float ts   = tp[0];
    const float l_t  = lp[0] * ts;
    const float taut = ap[0] / ts;

    int idx = f << 2;
    int i  = (idx >> 8) & 255;
    int j0 = idx & 255;
    bool hasUp = (i > 0), hasDn = (i < HH - 1);
    bool hasL  = (j0 > 0), hasR = (j0 < WW - 4);

    // --- u_old loads: rows i-1, i, i+1 (fp16 -> fp32) ---
    float u1c[4], u2c[4], u1u[4], u2u[4], u1d[4], u2d[4];
    ld4h(u1i, f, u1c); ld4h(u2i, f, u2c);
    if (hasUp) { ld4h(u1i, f - ROW4, u1u); ld4h(u2i, f - ROW4, u2u); }
    else { u1u[0]=u1u[1]=u1u[2]=u1u[3]=0.f; u2u[0]=u2u[1]=u2u[2]=u2u[3]=0.f; }
    if (hasDn) { ld4h(u1i, f + ROW4, u1d); ld4h(u2i, f + ROW4, u2d); }
    else { u1d[0]=u1d[1]=u1d[2]=u1d[3]=0.f; u2d[0]=u2d[1]=u2d[2]=u2d[3]=0.f; }
    float u1l  = hasL ? __half2float(u1i[idx - 1]) : 0.f;
    float u2l  = hasL ? __half2float(u2i[idx - 1]) : 0.f;
    float u1r  = hasR ? __half2float(u1i[idx + 4]) : 0.f;
    float u2r  = hasR ? __half2float(u2i[idx + 4]) : 0.f;
    float u1ur = (hasUp && hasR) ? __half2float(u1i[idx - WW + 4]) : 0.f;
    float u2ur = (hasUp && hasR) ? __half2float(u2i[idx - WW + 4]) : 0.f;
    float u1dl = (hasDn && hasL) ? __half2float(u1i[idx + WW - 1]) : 0.f;
    float u2dl = (hasDn && hasL) ? __half2float(u2i[idx + WW - 1]) : 0.f;

    // --- p_old loads ---
    float c11[4], c12[4], c21[4], c22[4];
    float p12uo[4], p22uo[4];
    float p11lo = 0.f, p21lo = 0.f;
    if (!P0) {
        ld4h(p11i, f, c11); ld4h(p12i, f, c12);
        ld4h(p21i, f, c21); ld4h(p22i, f, c22);
        if (hasUp) { ld4h(p12i, f - ROW4, p12uo); ld4h(p22i, f - ROW4, p22uo); }
        else { p12uo[0]=p12uo[1]=p12uo[2]=p12uo[3]=0.f;
               p22uo[0]=p22uo[1]=p22uo[2]=p22uo[3]=0.f; }
        if (hasL) { p11lo = __half2float(p11i[idx - 1]);
                    p21lo = __half2float(p21i[idx - 1]); }
    } else {
        #pragma unroll
        for (int k = 0; k < 4; ++k) {
            c11[k]=c12[k]=c21[k]=c22[k]=0.f; p12uo[k]=p22uo[k]=0.f;
        }
    }

    // --- p_new: own 4 pixels ---
    float p11n[4], p12n[4], p21n[4], p22n[4];
    #pragma unroll
    for (int k = 0; k < 4; ++k) {
        int j = j0 + k;
        float u1x = (j < WW-1) ? ((k < 3) ? u1c[k+1] : u1r) - u1c[k] : 0.f;
        float u2x = (j < WW-1) ? ((k < 3) ? u2c[k+1] : u2r) - u2c[k] : 0.f;
        float u1y = hasDn ? u1d[k] - u1c[k] : 0.f;
        float u2y = hasDn ? u2d[k] - u2c[k] : 0.f;
        pupd(c11[k], c12[k], u1x, u1y, taut, p11n[k], p12n[k]);
        pupd(c21[k], c22[k], u2x, u2y, taut, p21n[k], p22n[k]);
    }

    // --- p_new halo: left pixel (p11, p21) ---
    float p11nl = 0.f, p21nl = 0.f;
    if (hasL) {
        float u1x = u1c[0] - u1l;
        float u2x = u2c[0] - u2l;
        float u1y = hasDn ? u1dl - u1l : 0.f;
        float u2y = hasDn ? u2dl - u2l : 0.f;
        float d0, d1;
        pupd(p11lo, 0.f, u1x, u1y, taut, p11nl, d0);
        pupd(p21lo, 0.f, u2x, u2y, taut, p21nl, d1);
    }

    // --- p_new halo: up row (p12, p22) ---
    float p12nu[4] = {0.f,0.f,0.f,0.f}, p22nu[4] = {0.f,0.f,0.f,0.f};
    if (hasUp) {
        #pragma unroll
        for (int k = 0; k < 4; ++k) {
            int j = j0 + k;
            float u1x = (j < WW-1) ? ((k < 3) ? u1u[k+1] : u1ur) - u1u[k] : 0.f;
            float u2x = (j < WW-1) ? ((k < 3) ? u2u[k+1] : u2ur) - u2u[k] : 0.f;
            float u1y = u1c[k] - u1u[k];
            float u2y = u2c[k] - u2u[k];
            float d0, d1;
            pupd(0.f, p12uo[k], u1x, u1y, taut, d0, p12nu[k]);
            pupd(0.f, p22uo[k], u2x, u2y, taut, d1, p22nu[k]);
        }
    }

    // --- u-update with unrounded p_new ---
    float gx[4], gy[4];
    ld4h(g2x, f, gx); ld4h(g2y, f, gy);
    float4 rc4 = ld4(rc, f);
    const float* rcv = (const float*)&rc4;

    float u1n[4], u2n[4];
    #pragma unroll
    for (int k = 0; k < 4; ++k) {
        int j = j0 + k;
        float t11 = (j < WW-1) ? p11n[k] : 0.f;
        float l11 = (k == 0) ? p11nl : p11n[k-1];
        float t21 = (j < WW-1) ? p21n[k] : 0.f;
        float l21 = (k == 0) ? p21nl : p21n[k-1];
        float t12 = hasDn ? p12n[k] : 0.f;
        float t22 = hasDn ? p22n[k] : 0.f;
        float div1 = (t11 - l11) + (t12 - p12nu[k]);
        float div2 = (t21 - l21) + (t22 - p22nu[k]);

        float grad = gx[k]*gx[k] + gy[k]*gy[k] + EPSF;
        float rho  = rcv[k] + gx[k]*u1c[k] + gy[k]*u2c[k] + EPSF;
        float v1, v2;
        thresh(gx[k], gy[k], rho, grad, l_t, v1, v2);
        u1n[k] = v1 + u1c[k] + ts * div1;
        u2n[k] = v2 + u2c[k] + ts * div2;
    }

    if (LAST) {
        st4(u1f, f, u1n); st4(u2f, f, u2n);
    } else {
        st4h(u1o, f, u1n); st4h(u2o, f, u2n);
        st4h(p11o, f, p11n); st4h(p12o, f, p12n);
        st4h(p21o, f, p21n); st4h(p22o, f, p22n);
    }
}

// ---------------------------------------------------------------------------
extern "C" void kernel_launch(void* const* d_in, const int* in_sizes, int n_in,
                              void* d_out, int out_size, void* d_ws, size_t ws_size,
                              hipStream_t stream) {
    const float* x = (const float*)d_in[0];
    const float* y = (const float*)d_in[1];
    const float* t = (const float*)d_in[8];
    const float* l = (const float*)d_in[9];
    const float* a = (const float*)d_in[10];

    float* u1out = (float*)d_out;
    float* u2out = u1out + NPIX;

    // ws: rc(f32) + 14 fp16 fields (g x2, uA/uB x4, pA/pB x8) = ~134 MB
    char* ws = (char*)d_ws;
    float*  rcp_ = (float*)ws;                               ws += (size_t)NPIX * 4;
    __half* g2x  = (__half*)ws;                              ws += (size_t)NPIX * 2;
    __half* g2y  = (__half*)ws;                              ws += (size_t)NPIX * 2;
    __half* u1A  = (__half*)ws;                              ws += (size_t)NPIX * 2;
    __half* u2A  = (__half*)ws;                              ws += (size_t)NPIX * 2;
    __half* u1B  = (__half*)ws;                              ws += (size_t)NPIX * 2;
    __half* u2B  = (__half*)ws;                              ws += (size_t)NPIX * 2;
    __half* p11A = (__half*)ws;                              ws += (size_t)NPIX * 2;
    __half* p12A = (__half*)ws;                              ws += (size_t)NPIX * 2;
    __half* p21A = (__half*)ws;                              ws += (size_t)NPIX * 2;
    __half* p22A = (__half*)ws;                              ws += (size_t)NPIX * 2;
    __half* p11B = (__half*)ws;                              ws += (size_t)NPIX * 2;
    __half* p12B = (__half*)ws;                              ws += (size_t)NPIX * 2;
    __half* p21B = (__half*)ws;                              ws += (size_t)NPIX * 2;
    __half* p22B = (__half*)ws;

    dim3 block(NTHR), grid(NBLK);

    // S: g, rc, u0 -> uA
    s_kernel<<<grid, block, 0, stream>>>(x, y, g2x, g2y, rcp_, u1A, u2A, t, l);

    // F1: (p1 from p=0, u1). u: A->B, p: ->A
    f_kernel<true, false><<<grid, block, 0, stream>>>(
        g2x, g2y, rcp_, u1A, u2A,
        p11A, p12A, p21A, p22A,       // unused (P0)
        u1B, u2B, nullptr, nullptr,
        p11A, p12A, p21A, p22A, t, l, a);

    // F2..F8: u: B->A->B..., p: A->B->A...
    __half* u1s[2] = {u1A, u1B};
    __half* u2s[2] = {u2A, u2B};
    __half* p11s[2] = {p11A, p11B};
    __half* p12s[2] = {p12A, p12B};
    __half* p21s[2] = {p21A, p21B};
    __half* p22s[2] = {p22A, p22B};
    for (int k = 2; k <= 8; ++k) {
        int ui = (k & 1) ? 0 : 1;     // u_in:  k even -> B, k odd -> A
        int pi = (k & 1) ? 1 : 0;     // p_in:  k even -> A, k odd -> B
        f_kernel<false, false><<<grid, block, 0, stream>>>(
            g2x, g2y, rcp_, u1s[ui], u2s[ui],
            p11s[pi], p12s[pi], p21s[pi], p22s[pi],
            u1s[1 - ui], u2s[1 - ui], nullptr, nullptr,
            p11s[1 - pi], p12s[1 - pi], p21s[1 - pi], p22s[1 - pi], t, l, a);
    }

    // F9: u_in = uA (F8's out), p_in = pB (F8's out); write fp32 d_out.
    f_kernel<false, true><<<grid, block, 0, stream>>>(
        g2x, g2y, rcp_, u1A, u2A,
        p11B, p12B, p21B, p22B,
        nullptr, nullptr, u1out, u2out,
        p11A, p12A, p21A, p22A, t, l, a);
}

// Round 9
// 349.441 us; speedup vs baseline: 1.2490x; 1.2196x over previous
//
#include <hip/hip_runtime.h>
#include <hip/hip_fp16.h>

#define HH 256
#define WW 256
#define NB 64
#define NPIX (NB * HH * WW)      // 4,194,304 pixels
#define NF4  (NPIX / 4)          // 1,048,576 groups of 4
#define ROW4 (WW / 4)            // 64 groups per image row
#define EPSF 1e-12f
#define NTHR 256
#define NBLK (NF4 / NTHR)        // 4096 blocks (S kernel, flat)
#define TRH 4                    // F tile: 4 rows x 256 cols
#define FBLK (NB * (HH / TRH))   // 4096 blocks (F kernel, tiled)

__device__ __forceinline__ float4 ld4(const float* p, int f) {
    return ((const float4*)p)[f];
}
__device__ __forceinline__ void st4(float* p, int f, const float* v) {
    ((float4*)p)[f] = make_float4(v[0], v[1], v[2], v[3]);
}
__device__ __forceinline__ void ld4h(const __half* p, int f, float* o) {
    float2 raw = ((const float2*)p)[f];
    __half2 h0 = *(__half2*)&raw.x;
    __half2 h1 = *(__half2*)&raw.y;
    float2 a = __half22float2(h0), b = __half22float2(h1);
    o[0] = a.x; o[1] = a.y; o[2] = b.x; o[3] = b.y;
}
__device__ __forceinline__ void st4h(__half* p, int f, const float* v) {
    __half2 h0 = __floats2half2_rn(v[0], v[1]);
    __half2 h1 = __floats2half2_rn(v[2], v[3]);
    float2 raw;
    raw.x = *(float*)&h0; raw.y = *(float*)&h1;
    ((float2*)p)[f] = raw;
}

// TV-L1 thresholding step.
__device__ __forceinline__ void thresh(
    float gx, float gy, float rho, float grad, float l_t,
    float& v1, float& v2)
{
    float th = l_t * grad;
    if (rho < -th)      { v1 =  l_t * gx; v2 =  l_t * gy; }
    else if (rho > th)  { v1 = -l_t * gx; v2 = -l_t * gy; }
    else                { float s = -rho / grad; v1 = s * gx; v2 = s * gy; }
}

// p-pair update at one pixel for one flow.
__device__ __forceinline__ void pupd(
    float pao, float pbo, float ux, float uy, float taut,
    float& pa, float& pb)
{
    float n = sqrtf(ux * ux + uy * uy + EPSF);
    float r = 1.f / (1.f + taut * n);
    pa = (pao + taut * ux) * r;
    pb = (pbo + taut * uy) * r;
}

// ---------------------------------------------------------------------------
// S: g2x/g2y (fp16) + rc (fp32) from x,y; iteration-0 u-update (u = v, fp16).
// ---------------------------------------------------------------------------
__global__ __launch_bounds__(NTHR) void s_kernel(
    const float* __restrict__ x, const float* __restrict__ y,
    __half* __restrict__ g2x, __half* __restrict__ g2y, float* __restrict__ rc,
    __half* __restrict__ u1, __half* __restrict__ u2,
    const float* __restrict__ tp, const float* __restrict__ lp)
{
    int f = blockIdx.x * NTHR + threadIdx.x;
    const float l_t = lp[0] * tp[0];

    int idx = f << 2;
    int i  = (idx >> 8) & 255;
    int j0 = idx & 255;

    float4 xc4 = ld4(x, f), yc4 = ld4(y, f);
    const float* xc = (const float*)&xc4;
    const float* yc = (const float*)&yc4;

    float4 a4, b4;                       // wave-uniform row branch
    if (i == 0)            { a4 = ld4(x, f + ROW4); b4 = xc4; }
    else if (i == HH - 1)  { a4 = xc4; b4 = ld4(x, f - ROW4); }
    else                   { a4 = ld4(y, f + ROW4); b4 = ld4(y, f - ROW4); }
    const float* aa = (const float*)&a4;
    const float* bb = (const float*)&b4;

    float yl = (j0 > 0)      ? y[idx - 1] : 0.f;
    float yr = (j0 < WW - 4) ? y[idx + 4] : 0.f;

    float gxo[4], gyo[4], rco[4], u1o[4], u2o[4];
    #pragma unroll
    for (int k = 0; k < 4; ++k) {
        int j = j0 + k;
        float gx;
        if (j == 0)            gx = 0.5f * (xc[1] - xc[0]);
        else if (j == WW - 1)  gx = 0.5f * (xc[3] - xc[2]);
        else {
            float ynext = (k < 3) ? yc[k + 1] : yr;
            float yprev = (k > 0) ? yc[k - 1] : yl;
            gx = 0.5f * (ynext - yprev);
        }
        float gy = 0.5f * (aa[k] - bb[k]);
        // quantize g to fp16 NOW so iteration 0 matches iterations 1..9
        gx = __half2float(__float2half_rn(gx));
        gy = __half2float(__float2half_rn(gy));
        float rcv = yc[k] - xc[k];
        float grad = gx * gx + gy * gy + EPSF;
        float rho  = rcv + EPSF;
        float v1, v2;
        thresh(gx, gy, rho, grad, l_t, v1, v2);
        gxo[k] = gx; gyo[k] = gy; rco[k] = rcv;
        u1o[k] = v1; u2o[k] = v2;
    }
    st4h(g2x, f, gxo); st4h(g2y, f, gyo); st4(rc, f, rco);
    st4h(u1, f, u1o);  st4h(u2, f, u2o);
}

// ---------------------------------------------------------------------------
// F: fused p-update(it) + u-update(it+1), one block = 4 rows x 256 cols tile.
// Phase 1: p_new for own 4 px -> LDS (fp32); wave 0 also computes the up-halo
//          row's p12/p22. One __syncthreads.
// Phase 2: u-update reading left/up p_new from LDS.
// P0: p_old == 0. LAST: write u as fp32 to d_out, skip p stores.
// ---------------------------------------------------------------------------
template <bool P0, bool LAST>
__global__ __launch_bounds__(NTHR) void f_kernel(
    const __half* __restrict__ g2x, const __half* __restrict__ g2y,
    const float* __restrict__ rc,
    const __half* __restrict__ u1i, const __half* __restrict__ u2i,
    const __half* __restrict__ p11i, const __half* __restrict__ p12i,
    const __half* __restrict__ p21i, const __half* __restrict__ p22i,
    __half* __restrict__ u1o, __half* __restrict__ u2o,
    float* __restrict__ u1f, float* __restrict__ u2f,
    __half* __restrict__ p11o, __half* __restrict__ p12o,
    __half* __restrict__ p21o, __half* __restrict__ p22o,
    const float* __restrict__ tp, const float* __restrict__ lp,
    const float* __restrict__ ap)
{
    __shared__ float s11[TRH][WW];       // p11_new, tile rows 0..3
    __shared__ float s21[TRH][WW];       // p21_new
    __shared__ float s12[TRH + 1][WW];   // p12_new, row 0 = up-halo (i0-1)
    __shared__ float s22[TRH + 1][WW];   // p22_new

    const float ts   = tp[0];
    const float l_t  = lp[0] * ts;
    const float taut = ap[0] / ts;

    const int t    = threadIdx.x;
    const int tile = blockIdx.x;
    const int i0   = (tile & 63) * TRH;          // tile top row
    const int base = (tile >> 6) * (HH * WW);    // batch offset

    const int tr = t >> 6;          // tile row 0..3
    const int tc = (t & 63) * 4;    // first col of this thread's 4-px group
    const int r  = i0 + tr;         // global row
    const int f  = (base + r * WW + tc) >> 2;

    const bool hasDn = (r < HH - 1);

    // ---- Phase 1: own p_new ----
    float u1c[4], u2c[4], u1d[4], u2d[4];
    ld4h(u1i, f, u1c); ld4h(u2i, f, u2c);
    if (hasDn) { ld4h(u1i, f + ROW4, u1d); ld4h(u2i, f + ROW4, u2d); }
    else { u1d[0]=u1d[1]=u1d[2]=u1d[3]=0.f; u2d[0]=u2d[1]=u2d[2]=u2d[3]=0.f; }
    float u1r = (tc < WW - 4) ? __half2float(u1i[(f << 2) + 4]) : 0.f;
    float u2r = (tc < WW - 4) ? __half2float(u2i[(f << 2) + 4]) : 0.f;

    float c11[4], c12[4], c21[4], c22[4];
    if (!P0) {
        ld4h(p11i, f, c11); ld4h(p12i, f, c12);
        ld4h(p21i, f, c21); ld4h(p22i, f, c22);
    } else {
        #pragma unroll
        for (int k = 0; k < 4; ++k) { c11[k]=c12[k]=c21[k]=c22[k]=0.f; }
    }

    float p11n[4], p12n[4], p21n[4], p22n[4];
    #pragma unroll
    for (int k = 0; k < 4; ++k) {
        int j = tc + k;
        float u1x = (j < WW-1) ? ((k < 3) ? u1c[k+1] : u1r) - u1c[k] : 0.f;
        float u2x = (j < WW-1) ? ((k < 3) ? u2c[k+1] : u2r) - u2c[k] : 0.f;
        float u1y = hasDn ? u1d[k] - u1c[k] : 0.f;
        float u2y = hasDn ? u2d[k] - u2c[k] : 0.f;
        pupd(c11[k], c12[k], u1x, u1y, taut, p11n[k], p12n[k]);
        pupd(c21[k], c22[k], u2x, u2y, taut, p21n[k], p22n[k]);
    }
    *(float4*)&s11[tr][tc]     = make_float4(p11n[0], p11n[1], p11n[2], p11n[3]);
    *(float4*)&s21[tr][tc]     = make_float4(p21n[0], p21n[1], p21n[2], p21n[3]);
    *(float4*)&s12[tr + 1][tc] = make_float4(p12n[0], p12n[1], p12n[2], p12n[3]);
    *(float4*)&s22[tr + 1][tc] = make_float4(p22n[0], p22n[1], p22n[2], p22n[3]);

    // ---- Phase 1b: up-halo row (p12/p22 at global row i0-1), wave 0 only ----
    if (t < 64) {
        int hc = t * 4;
        float h12[4] = {0.f,0.f,0.f,0.f}, h22[4] = {0.f,0.f,0.f,0.f};
        if (i0 > 0) {
            int hrow = i0 - 1;
            int fh = (base + hrow * WW + hc) >> 2;
            float v1c[4], v2c[4], v1d[4], v2d[4];
            ld4h(u1i, fh, v1c); ld4h(u2i, fh, v2c);
            ld4h(u1i, fh + ROW4, v1d); ld4h(u2i, fh + ROW4, v2d); // row i0 (<HH)
            float v1r = (hc < WW - 4) ? __half2float(u1i[(fh << 2) + 4]) : 0.f;
            float v2r = (hc < WW - 4) ? __half2float(u2i[(fh << 2) + 4]) : 0.f;
            float h12o[4], h22o[4];
            if (!P0) { ld4h(p12i, fh, h12o); ld4h(p22i, fh, h22o); }
            else { h12o[0]=h12o[1]=h12o[2]=h12o[3]=0.f;
                   h22o[0]=h22o[1]=h22o[2]=h22o[3]=0.f; }
            #pragma unroll
            for (int k = 0; k < 4; ++k) {
                int j = hc + k;
                float u1x = (j < WW-1) ? ((k < 3) ? v1c[k+1] : v1r) - v1c[k] : 0.f;
                float u2x = (j < WW-1) ? ((k < 3) ? v2c[k+1] : v2r) - v2c[k] : 0.f;
                float u1y = v1d[k] - v1c[k];   // i0-1 < HH-1 always
                float u2y = v2d[k] - v2c[k];
                float d0, d1;
                pupd(0.f, h12o[k], u1x, u1y, taut, d0, h12[k]);
                pupd(0.f, h22o[k], u2x, u2y, taut, d1, h22[k]);
            }
        }
        *(float4*)&s12[0][hc] = make_float4(h12[0], h12[1], h12[2], h12[3]);
        *(float4*)&s22[0][hc] = make_float4(h22[0], h22[1], h22[2], h22[3]);
    }
    __syncthreads();

    // ---- Phase 2: u-update ----
    float l11 = (tc > 0) ? s11[tr][tc - 1] : 0.f;
    float l21 = (tc > 0) ? s21[tr][tc - 1] : 0.f;
    float4 l12v = *(const float4*)&s12[tr][tc];   // p12_new at row r-1 (or 0)
    float4 l22v = *(const float4*)&s22[tr][tc];
    const float* l12 = (const float*)&l12v;
    const float* l22 = (const float*)&l22v;

    float gx[4], gy[4];
    ld4h(g2x, f, gx); ld4h(g2y, f, gy);
    float4 rc4 = ld4(rc, f);
    const float* rcv = (const float*)&rc4;

    float u1n[4], u2n[4];
    #pragma unroll
    for (int k = 0; k < 4; ++k) {
        int j = tc + k;
        float t11 = (j < WW-1) ? p11n[k] : 0.f;
        float l11k = (k == 0) ? l11 : p11n[k-1];
        float t21 = (j < WW-1) ? p21n[k] : 0.f;
        float l21k = (k == 0) ? l21 : p21n[k-1];
        float t12 = hasDn ? p12n[k] : 0.f;
        float t22 = hasDn ? p22n[k] : 0.f;
        float div1 = (t11 - l11k) + (t12 - l12[k]);
        float div2 = (t21 - l21k) + (t22 - l22[k]);

        float grad = gx[k]*gx[k] + gy[k]*gy[k] + EPSF;
        float rho  = rcv[k] + gx[k]*u1c[k] + gy[k]*u2c[k] + EPSF;
        float v1, v2;
        thresh(gx[k], gy[k], rho, grad, l_t, v1, v2);
        u1n[k] = v1 + u1c[k] + ts * div1;
        u2n[k] = v2 + u2c[k] + ts * div2;
    }

    if (LAST) {
        st4(u1f, f, u1n); st4(u2f, f, u2n);
    } else {
        st4h(u1o, f, u1n); st4h(u2o, f, u2n);
        st4h(p11o, f, p11n); st4h(p12o, f, p12n);
        st4h(p21o, f, p21n); st4h(p22o, f, p22n);
    }
}

// ---------------------------------------------------------------------------
extern "C" void kernel_launch(void* const* d_in, const int* in_sizes, int n_in,
                              void* d_out, int out_size, void* d_ws, size_t ws_size,
                              hipStream_t stream) {
    const float* x = (const float*)d_in[0];
    const float* y = (const float*)d_in[1];
    const float* t = (const float*)d_in[8];
    const float* l = (const float*)d_in[9];
    const float* a = (const float*)d_in[10];

    float* u1out = (float*)d_out;
    float* u2out = u1out + NPIX;

    // ws: rc(f32) + 14 fp16 fields (g x2, uA/uB x4, pA/pB x8) = ~134 MB
    char* ws = (char*)d_ws;
    float*  rcp_ = (float*)ws;                               ws += (size_t)NPIX * 4;
    __half* g2x  = (__half*)ws;                              ws += (size_t)NPIX * 2;
    __half* g2y  = (__half*)ws;                              ws += (size_t)NPIX * 2;
    __half* u1A  = (__half*)ws;                              ws += (size_t)NPIX * 2;
    __half* u2A  = (__half*)ws;                              ws += (size_t)NPIX * 2;
    __half* u1B  = (__half*)ws;                              ws += (size_t)NPIX * 2;
    __half* u2B  = (__half*)ws;                              ws += (size_t)NPIX * 2;
    __half* p11A = (__half*)ws;                              ws += (size_t)NPIX * 2;
    __half* p12A = (__half*)ws;                              ws += (size_t)NPIX * 2;
    __half* p21A = (__half*)ws;                              ws += (size_t)NPIX * 2;
    __half* p22A = (__half*)ws;                              ws += (size_t)NPIX * 2;
    __half* p11B = (__half*)ws;                              ws += (size_t)NPIX * 2;
    __half* p12B = (__half*)ws;                              ws += (size_t)NPIX * 2;
    __half* p21B = (__half*)ws;                              ws += (size_t)NPIX * 2;
    __half* p22B = (__half*)ws;

    dim3 block(NTHR);

    // S: g, rc, u0 -> uA
    s_kernel<<<dim3(NBLK), block, 0, stream>>>(x, y, g2x, g2y, rcp_,
                                               u1A, u2A, t, l);

    // F1: (p1 from p=0, u1). u: A->B, p: ->A
    f_kernel<true, false><<<dim3(FBLK), block, 0, stream>>>(
        g2x, g2y, rcp_, u1A, u2A,
        p11A, p12A, p21A, p22A,       // unused (P0)
        u1B, u2B, nullptr, nullptr,
        p11A, p12A, p21A, p22A, t, l, a);

    // F2..F8: u: B->A->B..., p: A->B->A...
    __half* u1s[2] = {u1A, u1B};
    __half* u2s[2] = {u2A, u2B};
    __half* p11s[2] = {p11A, p11B};
    __half* p12s[2] = {p12A, p12B};
    __half* p21s[2] = {p21A, p21B};
    __half* p22s[2] = {p22A, p22B};
    for (int k = 2; k <= 8; ++k) {
        int ui = (k & 1) ? 0 : 1;     // u_in:  k even -> B, k odd -> A
        int pi = (k & 1) ? 1 : 0;     // p_in:  k even -> A, k odd -> B
        f_kernel<false, false><<<dim3(FBLK), block, 0, stream>>>(
            g2x, g2y, rcp_, u1s[ui], u2s[ui],
            p11s[pi], p12s[pi], p21s[pi], p22s[pi],
            u1s[1 - ui], u2s[1 - ui], nullptr, nullptr,
            p11s[1 - pi], p12s[1 - pi], p21s[1 - pi], p22s[1 - pi], t, l, a);
    }

    // F9: u_in = uA (F8's out), p_in = pB (F8's out); write fp32 d_out.
    f_kernel<false, true><<<dim3(FBLK), block, 0, stream>>>(
        g2x, g2y, rcp_, u1A, u2A,
        p11B, p12B, p21B, p22B,
        nullptr, nullptr, u1out, u2out,
        p11A, p12A, p21A, p22A, t, l, a);
}

// Round 10
// 330.591 us; speedup vs baseline: 1.3202x; 1.0570x over previous
//
#include <hip/hip_runtime.h>
#include <hip/hip_fp16.h>

#define HH 256
#define WW 256
#define NB 64
#define NPIX (NB * HH * WW)      // 4,194,304 pixels
#define NF4  (NPIX / 4)          // 1,048,576 groups of 4
#define ROW4 (WW / 4)            // 64 groups per image row
#define EPSF 1e-12f
#define NTHR 256
#define NBLK (NF4 / NTHR)        // 4096 blocks (S kernel, flat)
#define TRH 4                    // F tile: 4 rows x 256 cols
#define FBLK (NB * (HH / TRH))   // 4096 blocks (F kernel, tiled)

__device__ __forceinline__ float4 ld4(const float* p, int f) {
    return ((const float4*)p)[f];
}
__device__ __forceinline__ void st4(float* p, int f, const float* v) {
    ((float4*)p)[f] = make_float4(v[0], v[1], v[2], v[3]);
}
// Packed-pair load: 4 pixels of a __half2 field (16B) -> two float[4]
__device__ __forceinline__ void ld8h(const __half2* p, int f, float* a, float* b) {
    float4 raw = ((const float4*)p)[f];
    const __half2* h = (const __half2*)&raw;
    #pragma unroll
    for (int k = 0; k < 4; ++k) {
        float2 v = __half22float2(h[k]);
        a[k] = v.x; b[k] = v.y;
    }
}
__device__ __forceinline__ void st8h(__half2* p, int f, const float* a, const float* b) {
    float4 raw;
    __half2* h = (__half2*)&raw;
    #pragma unroll
    for (int k = 0; k < 4; ++k) h[k] = __floats2half2_rn(a[k], b[k]);
    ((float4*)p)[f] = raw;
}

// TV-L1 thresholding step.
__device__ __forceinline__ void thresh(
    float gx, float gy, float rho, float grad, float l_t,
    float& v1, float& v2)
{
    float th = l_t * grad;
    if (rho < -th)      { v1 =  l_t * gx; v2 =  l_t * gy; }
    else if (rho > th)  { v1 = -l_t * gx; v2 = -l_t * gy; }
    else                { float s = -rho / grad; v1 = s * gx; v2 = s * gy; }
}

// p-pair update at one pixel for one flow.
__device__ __forceinline__ void pupd(
    float pao, float pbo, float ux, float uy, float taut,
    float& pa, float& pb)
{
    float n = sqrtf(ux * ux + uy * uy + EPSF);
    float r = 1.f / (1.f + taut * n);
    pa = (pao + taut * ux) * r;
    pb = (pbo + taut * uy) * r;
}

// ---------------------------------------------------------------------------
// S: packed g=(gx,gy) fp16x2, rc fp32, u0=(u1,u2) fp16x2 from x,y.
// ---------------------------------------------------------------------------
__global__ __launch_bounds__(NTHR) void s_kernel(
    const float* __restrict__ x, const float* __restrict__ y,
    __half2* __restrict__ ga, float* __restrict__ rc,
    __half2* __restrict__ up,
    const float* __restrict__ tp, const float* __restrict__ lp)
{
    int f = blockIdx.x * NTHR + threadIdx.x;
    const float l_t = lp[0] * tp[0];

    int idx = f << 2;
    int i  = (idx >> 8) & 255;
    int j0 = idx & 255;

    float4 xc4 = ld4(x, f), yc4 = ld4(y, f);
    const float* xc = (const float*)&xc4;
    const float* yc = (const float*)&yc4;

    float4 a4, b4;                       // wave-uniform row branch
    if (i == 0)            { a4 = ld4(x, f + ROW4); b4 = xc4; }
    else if (i == HH - 1)  { a4 = xc4; b4 = ld4(x, f - ROW4); }
    else                   { a4 = ld4(y, f + ROW4); b4 = ld4(y, f - ROW4); }
    const float* aa = (const float*)&a4;
    const float* bb = (const float*)&b4;

    float yl = (j0 > 0)      ? y[idx - 1] : 0.f;
    float yr = (j0 < WW - 4) ? y[idx + 4] : 0.f;

    float gxo[4], gyo[4], rco[4], u1o[4], u2o[4];
    #pragma unroll
    for (int k = 0; k < 4; ++k) {
        int j = j0 + k;
        float gx;
        if (j == 0)            gx = 0.5f * (xc[1] - xc[0]);
        else if (j == WW - 1)  gx = 0.5f * (xc[3] - xc[2]);
        else {
            float ynext = (k < 3) ? yc[k + 1] : yr;
            float yprev = (k > 0) ? yc[k - 1] : yl;
            gx = 0.5f * (ynext - yprev);
        }
        float gy = 0.5f * (aa[k] - bb[k]);
        // quantize g to fp16 NOW so iteration 0 matches iterations 1..9
        gx = __half2float(__float2half_rn(gx));
        gy = __half2float(__float2half_rn(gy));
        float rcv = yc[k] - xc[k];
        float grad = gx * gx + gy * gy + EPSF;
        float rho  = rcv + EPSF;
        float v1, v2;
        thresh(gx, gy, rho, grad, l_t, v1, v2);
        gxo[k] = gx; gyo[k] = gy; rco[k] = rcv;
        u1o[k] = v1; u2o[k] = v2;
    }
    st8h(ga, f, gxo, gyo); st4(rc, f, rco);
    st8h(up, f, u1o, u2o);
}

// ---------------------------------------------------------------------------
// F: fused p-update(it) + u-update(it+1), one block = 4 rows x 256 cols tile.
// All state packed: up=(u1,u2), pa=(p11,p12), pb=(p21,p22), ga=(gx,gy).
// Phase 1: p_new for own 4 px -> LDS (fp32); wave 0 also computes the up-halo
//          row's p12/p22. One __syncthreads. Phase 2: u-update.
// P0: p_old == 0. LAST: write u as fp32 to d_out, skip p/u-fp16 stores.
// ---------------------------------------------------------------------------
template <bool P0, bool LAST>
__global__ __launch_bounds__(NTHR) void f_kernel(
    const __half2* __restrict__ ga, const float* __restrict__ rc,
    const __half2* __restrict__ upi,
    const __half2* __restrict__ pai, const __half2* __restrict__ pbi,
    __half2* __restrict__ upo,
    float* __restrict__ u1f, float* __restrict__ u2f,
    __half2* __restrict__ pao, __half2* __restrict__ pbo,
    const float* __restrict__ tp, const float* __restrict__ lp,
    const float* __restrict__ ap)
{
    __shared__ float s11[TRH][WW];       // p11_new, tile rows 0..3
    __shared__ float s21[TRH][WW];       // p21_new
    __shared__ float s12[TRH + 1][WW];   // p12_new, row 0 = up-halo (i0-1)
    __shared__ float s22[TRH + 1][WW];   // p22_new

    const float ts   = tp[0];
    const float l_t  = lp[0] * ts;
    const float taut = ap[0] / ts;

    const int t    = threadIdx.x;
    const int tile = blockIdx.x;
    const int i0   = (tile & 63) * TRH;          // tile top row
    const int base = (tile >> 6) * (HH * WW);    // batch offset

    const int tr = t >> 6;          // tile row 0..3
    const int tc = (t & 63) * 4;    // first col of this thread's 4-px group
    const int r  = i0 + tr;         // global row
    const int f  = (base + r * WW + tc) >> 2;
    const int idx = f << 2;

    const bool hasDn = (r < HH - 1);

    // ---- Phase 1: own p_new ----
    float u1c[4], u2c[4], u1d[4], u2d[4];
    ld8h(upi, f, u1c, u2c);
    if (hasDn) ld8h(upi, f + ROW4, u1d, u2d);
    else { u1d[0]=u1d[1]=u1d[2]=u1d[3]=0.f; u2d[0]=u2d[1]=u2d[2]=u2d[3]=0.f; }
    float u1r = 0.f, u2r = 0.f;
    if (tc < WW - 4) {
        float2 v = __half22float2(upi[idx + 4]);
        u1r = v.x; u2r = v.y;
    }

    float c11[4], c12[4], c21[4], c22[4];
    if (!P0) {
        ld8h(pai, f, c11, c12);
        ld8h(pbi, f, c21, c22);
    } else {
        #pragma unroll
        for (int k = 0; k < 4; ++k) { c11[k]=c12[k]=c21[k]=c22[k]=0.f; }
    }

    float p11n[4], p12n[4], p21n[4], p22n[4];
    #pragma unroll
    for (int k = 0; k < 4; ++k) {
        int j = tc + k;
        float u1x = (j < WW-1) ? ((k < 3) ? u1c[k+1] : u1r) - u1c[k] : 0.f;
        float u2x = (j < WW-1) ? ((k < 3) ? u2c[k+1] : u2r) - u2c[k] : 0.f;
        float u1y = hasDn ? u1d[k] - u1c[k] : 0.f;
        float u2y = hasDn ? u2d[k] - u2c[k] : 0.f;
        pupd(c11[k], c12[k], u1x, u1y, taut, p11n[k], p12n[k]);
        pupd(c21[k], c22[k], u2x, u2y, taut, p21n[k], p22n[k]);
    }
    *(float4*)&s11[tr][tc]     = make_float4(p11n[0], p11n[1], p11n[2], p11n[3]);
    *(float4*)&s21[tr][tc]     = make_float4(p21n[0], p21n[1], p21n[2], p21n[3]);
    *(float4*)&s12[tr + 1][tc] = make_float4(p12n[0], p12n[1], p12n[2], p12n[3]);
    *(float4*)&s22[tr + 1][tc] = make_float4(p22n[0], p22n[1], p22n[2], p22n[3]);

    // ---- Phase 1b: up-halo row (p12/p22 at global row i0-1), wave 0 only ----
    if (t < 64) {
        int hc = t * 4;
        float h12[4] = {0.f,0.f,0.f,0.f}, h22[4] = {0.f,0.f,0.f,0.f};
        if (i0 > 0) {
            int hrow = i0 - 1;
            int fh = (base + hrow * WW + hc) >> 2;
            float v1c[4], v2c[4], v1d[4], v2d[4];
            ld8h(upi, fh, v1c, v2c);
            ld8h(upi, fh + ROW4, v1d, v2d);    // row i0 (< HH always)
            float v1r = 0.f, v2r = 0.f;
            if (hc < WW - 4) {
                float2 v = __half22float2(upi[(fh << 2) + 4]);
                v1r = v.x; v2r = v.y;
            }
            float h11o[4], h12o[4], h21o[4], h22o[4];
            if (!P0) { ld8h(pai, fh, h11o, h12o); ld8h(pbi, fh, h21o, h22o); }
            else { h12o[0]=h12o[1]=h12o[2]=h12o[3]=0.f;
                   h22o[0]=h22o[1]=h22o[2]=h22o[3]=0.f; }
            #pragma unroll
            for (int k = 0; k < 4; ++k) {
                int j = hc + k;
                float u1x = (j < WW-1) ? ((k < 3) ? v1c[k+1] : v1r) - v1c[k] : 0.f;
                float u2x = (j < WW-1) ? ((k < 3) ? v2c[k+1] : v2r) - v2c[k] : 0.f;
                float u1y = v1d[k] - v1c[k];   // i0-1 < HH-1 always
                float u2y = v2d[k] - v2c[k];
                float d0, d1;
                pupd(0.f, h12o[k], u1x, u1y, taut, d0, h12[k]);
                pupd(0.f, h22o[k], u2x, u2y, taut, d1, h22[k]);
            }
        }
        *(float4*)&s12[0][hc] = make_float4(h12[0], h12[1], h12[2], h12[3]);
        *(float4*)&s22[0][hc] = make_float4(h22[0], h22[1], h22[2], h22[3]);
    }
    __syncthreads();

    // ---- Phase 2: u-update ----
    float l11 = (tc > 0) ? s11[tr][tc - 1] : 0.f;
    float l21 = (tc > 0) ? s21[tr][tc - 1] : 0.f;
    float4 l12v = *(const float4*)&s12[tr][tc];   // p12_new at row r-1 (or 0)
    float4 l22v = *(const float4*)&s22[tr][tc];
    const float* l12 = (const float*)&l12v;
    const float* l22 = (const float*)&l22v;

    float gx[4], gy[4];
    ld8h(ga, f, gx, gy);
    float4 rc4 = ld4(rc, f);
    const float* rcv = (const float*)&rc4;

    float u1n[4], u2n[4];
    #pragma unroll
    for (int k = 0; k < 4; ++k) {
        int j = tc + k;
        float t11 = (j < WW-1) ? p11n[k] : 0.f;
        float l11k = (k == 0) ? l11 : p11n[k-1];
        float t21 = (j < WW-1) ? p21n[k] : 0.f;
        float l21k = (k == 0) ? l21 : p21n[k-1];
        float t12 = hasDn ? p12n[k] : 0.f;
        float t22 = hasDn ? p22n[k] : 0.f;
        float div1 = (t11 - l11k) + (t12 - l12[k]);
        float div2 = (t21 - l21k) + (t22 - l22[k]);

        float grad = gx[k]*gx[k] + gy[k]*gy[k] + EPSF;
        float rho  = rcv[k] + gx[k]*u1c[k] + gy[k]*u2c[k] + EPSF;
        float v1, v2;
        thresh(gx[k], gy[k], rho, grad, l_t, v1, v2);
        u1n[k] = v1 + u1c[k] + ts * div1;
        u2n[k] = v2 + u2c[k] + ts * div2;
    }

    if (LAST) {
        st4(u1f, f, u1n); st4(u2f, f, u2n);
    } else {
        st8h(upo, f, u1n, u2n);
        st8h(pao, f, p11n, p12n);
        st8h(pbo, f, p21n, p22n);
    }
}

// ---------------------------------------------------------------------------
extern "C" void kernel_launch(void* const* d_in, const int* in_sizes, int n_in,
                              void* d_out, int out_size, void* d_ws, size_t ws_size,
                              hipStream_t stream) {
    const float* x = (const float*)d_in[0];
    const float* y = (const float*)d_in[1];
    const float* t = (const float*)d_in[8];
    const float* l = (const float*)d_in[9];
    const float* a = (const float*)d_in[10];

    float* u1out = (float*)d_out;
    float* u2out = u1out + NPIX;

    // ws: rc(f32) + 7 packed half2 fields (ga, upA/upB, paA/pbA, paB/pbB)
    // = 8 * 16.8 MB = 134 MB
    char* ws = (char*)d_ws;
    float*   rcp_ = (float*)ws;                              ws += (size_t)NPIX * 4;
    __half2* gaP  = (__half2*)ws;                            ws += (size_t)NPIX * 4;
    __half2* upA  = (__half2*)ws;                            ws += (size_t)NPIX * 4;
    __half2* upB  = (__half2*)ws;                            ws += (size_t)NPIX * 4;
    __half2* paA  = (__half2*)ws;                            ws += (size_t)NPIX * 4;
    __half2* pbA  = (__half2*)ws;                            ws += (size_t)NPIX * 4;
    __half2* paB  = (__half2*)ws;                            ws += (size_t)NPIX * 4;
    __half2* pbB  = (__half2*)ws;

    dim3 block(NTHR);

    // S: ga, rc, u0 -> upA
    s_kernel<<<dim3(NBLK), block, 0, stream>>>(x, y, gaP, rcp_, upA, t, l);

    // F1: (p1 from p=0, u1). u: A->B, p: ->A
    f_kernel<true, false><<<dim3(FBLK), block, 0, stream>>>(
        gaP, rcp_, upA, paA, pbA,     // p_in unused (P0)
        upB, nullptr, nullptr, paA, pbA, t, l, a);

    // F2..F8: u: B->A->B..., p: A->B->A...
    __half2* ups[2] = {upA, upB};
    __half2* pas[2] = {paA, paB};
    __half2* pbs[2] = {pbA, pbB};
    for (int k = 2; k <= 8; ++k) {
        int ui = (k & 1) ? 0 : 1;     // u_in:  k even -> B, k odd -> A
        int pi = (k & 1) ? 1 : 0;     // p_in:  k even -> A, k odd -> B
        f_kernel<false, false><<<dim3(FBLK), block, 0, stream>>>(
            gaP, rcp_, ups[ui], pas[pi], pbs[pi],
            ups[1 - ui], nullptr, nullptr, pas[1 - pi], pbs[1 - pi], t, l, a);
    }

    // F9: u_in = upA (F8's out), p_in = paB/pbB (F8's out); write fp32 d_out.
    f_kernel<false, true><<<dim3(FBLK), block, 0, stream>>>(
        gaP, rcp_, upA, paB, pbB,
        nullptr, u1out, u2out, paA, pbA, t, l, a);
}

// Round 11
// 319.253 us; speedup vs baseline: 1.3671x; 1.0355x over previous
//
#include <hip/hip_runtime.h>
#include <hip/hip_fp16.h>

#define HH 256
#define WW 256
#define NB 64
#define NPIX (NB * HH * WW)      // 4,194,304 pixels
#define NF4  (NPIX / 4)          // 1,048,576 groups of 4
#define ROW4 (WW / 4)            // 64 groups per image row
#define EPSF 1e-12f
#define NTHR 256
#define NBLK (NF4 / NTHR)        // 4096 blocks (S kernel, flat)
#define FTRH 8                   // F tile: 8 rows x 256 cols
#define FTHR 512                 // F block threads (8 waves)
#define FBLK (NB * (HH / FTRH)) // 2048 blocks (F kernel)

__device__ __forceinline__ float4 ld4(const float* p, int f) {
    return ((const float4*)p)[f];
}
__device__ __forceinline__ void st4(float* p, int f, const float* v) {
    ((float4*)p)[f] = make_float4(v[0], v[1], v[2], v[3]);
}
// Packed-pair load: 4 pixels of a __half2 field (16B) -> two float[4]
__device__ __forceinline__ void ld8h(const __half2* p, int f, float* a, float* b) {
    float4 raw = ((const float4*)p)[f];
    const __half2* h = (const __half2*)&raw;
    #pragma unroll
    for (int k = 0; k < 4; ++k) {
        float2 v = __half22float2(h[k]);
        a[k] = v.x; b[k] = v.y;
    }
}
__device__ __forceinline__ void st8h(__half2* p, int f, const float* a, const float* b) {
    float4 raw;
    __half2* h = (__half2*)&raw;
    #pragma unroll
    for (int k = 0; k < 4; ++k) h[k] = __floats2half2_rn(a[k], b[k]);
    ((float4*)p)[f] = raw;
}
// Pack 4 px of two fields into 4 __half2 inside a float4 (for LDS 16B store)
__device__ __forceinline__ float4 pack4h2(const float* a, const float* b) {
    float4 raw;
    __half2* h = (__half2*)&raw;
    #pragma unroll
    for (int k = 0; k < 4; ++k) h[k] = __floats2half2_rn(a[k], b[k]);
    return raw;
}

// TV-L1 thresholding step.
__device__ __forceinline__ void thresh(
    float gx, float gy, float rho, float grad, float l_t,
    float& v1, float& v2)
{
    float th = l_t * grad;
    if (rho < -th)      { v1 =  l_t * gx; v2 =  l_t * gy; }
    else if (rho > th)  { v1 = -l_t * gx; v2 = -l_t * gy; }
    else                { float s = -rho / grad; v1 = s * gx; v2 = s * gy; }
}

// p-pair update at one pixel for one flow.
__device__ __forceinline__ void pupd(
    float pao, float pbo, float ux, float uy, float taut,
    float& pa, float& pb)
{
    float n = sqrtf(ux * ux + uy * uy + EPSF);
    float r = 1.f / (1.f + taut * n);
    pa = (pao + taut * ux) * r;
    pb = (pbo + taut * uy) * r;
}

// ---------------------------------------------------------------------------
// S: packed g=(gx,gy) fp16x2, rc fp32, u0=(u1,u2) fp16x2 from x,y.
// ---------------------------------------------------------------------------
__global__ __launch_bounds__(NTHR) void s_kernel(
    const float* __restrict__ x, const float* __restrict__ y,
    __half2* __restrict__ ga, float* __restrict__ rc,
    __half2* __restrict__ up,
    const float* __restrict__ tp, const float* __restrict__ lp)
{
    int f = blockIdx.x * NTHR + threadIdx.x;
    const float l_t = lp[0] * tp[0];

    int idx = f << 2;
    int i  = (idx >> 8) & 255;
    int j0 = idx & 255;

    float4 xc4 = ld4(x, f), yc4 = ld4(y, f);
    const float* xc = (const float*)&xc4;
    const float* yc = (const float*)&yc4;

    float4 a4, b4;                       // wave-uniform row branch
    if (i == 0)            { a4 = ld4(x, f + ROW4); b4 = xc4; }
    else if (i == HH - 1)  { a4 = xc4; b4 = ld4(x, f - ROW4); }
    else                   { a4 = ld4(y, f + ROW4); b4 = ld4(y, f - ROW4); }
    const float* aa = (const float*)&a4;
    const float* bb = (const float*)&b4;

    float yl = (j0 > 0)      ? y[idx - 1] : 0.f;
    float yr = (j0 < WW - 4) ? y[idx + 4] : 0.f;

    float gxo[4], gyo[4], rco[4], u1o[4], u2o[4];
    #pragma unroll
    for (int k = 0; k < 4; ++k) {
        int j = j0 + k;
        float gx;
        if (j == 0)            gx = 0.5f * (xc[1] - xc[0]);
        else if (j == WW - 1)  gx = 0.5f * (xc[3] - xc[2]);
        else {
            float ynext = (k < 3) ? yc[k + 1] : yr;
            float yprev = (k > 0) ? yc[k - 1] : yl;
            gx = 0.5f * (ynext - yprev);
        }
        float gy = 0.5f * (aa[k] - bb[k]);
        // quantize g to fp16 NOW so iteration 0 matches iterations 1..9
        gx = __half2float(__float2half_rn(gx));
        gy = __half2float(__float2half_rn(gy));
        float rcv = yc[k] - xc[k];
        float grad = gx * gx + gy * gy + EPSF;
        float rho  = rcv + EPSF;
        float v1, v2;
        thresh(gx, gy, rho, grad, l_t, v1, v2);
        gxo[k] = gx; gyo[k] = gy; rco[k] = rcv;
        u1o[k] = v1; u2o[k] = v2;
    }
    st8h(ga, f, gxo, gyo); st4(rc, f, rco);
    st8h(up, f, u1o, u2o);
}

// ---------------------------------------------------------------------------
// F: fused p-update(it) + u-update(it+1), one block = 8 rows x 256 cols tile.
// Packed state: up=(u1,u2), pa=(p11,p12), pb=(p21,p22), ga=(gx,gy).
// LDS (fp16-packed): sA=(p11,p21) own rows; sB=(p12,p22) with up-halo row 0.
// Phase 1: own p_new -> LDS; threads 0..63 also compute the up-halo row's
// p12/p22. One __syncthreads. Phase 2: u-update.
// P0: p_old == 0. LAST: write u as fp32 to d_out, skip fp16 stores.
// ---------------------------------------------------------------------------
template <bool P0, bool LAST>
__global__ __launch_bounds__(FTHR) void f_kernel(
    const __half2* __restrict__ ga, const float* __restrict__ rc,
    const __half2* __restrict__ upi,
    const __half2* __restrict__ pai, const __half2* __restrict__ pbi,
    __half2* __restrict__ upo,
    float* __restrict__ u1f, float* __restrict__ u2f,
    __half2* __restrict__ pao, __half2* __restrict__ pbo,
    const float* __restrict__ tp, const float* __restrict__ lp,
    const float* __restrict__ ap)
{
    __shared__ __half2 sA[FTRH][WW];       // (p11,p21), tile rows 0..7
    __shared__ __half2 sB[FTRH + 1][WW];   // (p12,p22), row 0 = up-halo

    const float ts   = tp[0];
    const float l_t  = lp[0] * ts;
    const float taut = ap[0] / ts;

    const int t    = threadIdx.x;
    const int tile = blockIdx.x;
    const int i0   = (tile & 31) * FTRH;         // tile top row
    const int base = (tile >> 5) * (HH * WW);    // batch offset

    const int tr = t >> 6;          // tile row 0..7
    const int tc = (t & 63) * 4;    // first col of this thread's 4-px group
    const int r  = i0 + tr;         // global row
    const int f  = (base + r * WW + tc) >> 2;
    const int idx = f << 2;

    const bool hasDn = (r < HH - 1);

    // ---- Phase 1: own p_new ----
    float u1c[4], u2c[4], u1d[4], u2d[4];
    ld8h(upi, f, u1c, u2c);
    if (hasDn) ld8h(upi, f + ROW4, u1d, u2d);
    else { u1d[0]=u1d[1]=u1d[2]=u1d[3]=0.f; u2d[0]=u2d[1]=u2d[2]=u2d[3]=0.f; }
    float u1r = 0.f, u2r = 0.f;
    if (tc < WW - 4) {
        float2 v = __half22float2(upi[idx + 4]);
        u1r = v.x; u2r = v.y;
    }

    float c11[4], c12[4], c21[4], c22[4];
    if (!P0) {
        ld8h(pai, f, c11, c12);
        ld8h(pbi, f, c21, c22);
    } else {
        #pragma unroll
        for (int k = 0; k < 4; ++k) { c11[k]=c12[k]=c21[k]=c22[k]=0.f; }
    }

    float p11n[4], p12n[4], p21n[4], p22n[4];
    #pragma unroll
    for (int k = 0; k < 4; ++k) {
        int j = tc + k;
        float u1x = (j < WW-1) ? ((k < 3) ? u1c[k+1] : u1r) - u1c[k] : 0.f;
        float u2x = (j < WW-1) ? ((k < 3) ? u2c[k+1] : u2r) - u2c[k] : 0.f;
        float u1y = hasDn ? u1d[k] - u1c[k] : 0.f;
        float u2y = hasDn ? u2d[k] - u2c[k] : 0.f;
        pupd(c11[k], c12[k], u1x, u1y, taut, p11n[k], p12n[k]);
        pupd(c21[k], c22[k], u2x, u2y, taut, p21n[k], p22n[k]);
    }
    *(float4*)&sA[tr][tc]     = pack4h2(p11n, p21n);
    *(float4*)&sB[tr + 1][tc] = pack4h2(p12n, p22n);

    // ---- Phase 1b: up-halo row (p12/p22 at global row i0-1), threads 0..63 ----
    if (t < 64) {
        int hc = t * 4;
        float h12[4] = {0.f,0.f,0.f,0.f}, h22[4] = {0.f,0.f,0.f,0.f};
        if (i0 > 0) {
            int hrow = i0 - 1;
            int fh = (base + hrow * WW + hc) >> 2;
            float v1c[4], v2c[4], v1d[4], v2d[4];
            ld8h(upi, fh, v1c, v2c);
            ld8h(upi, fh + ROW4, v1d, v2d);    // row i0 (< HH always)
            float v1r = 0.f, v2r = 0.f;
            if (hc < WW - 4) {
                float2 v = __half22float2(upi[(fh << 2) + 4]);
                v1r = v.x; v2r = v.y;
            }
            float h11o[4], h12o[4], h21o[4], h22o[4];
            if (!P0) { ld8h(pai, fh, h11o, h12o); ld8h(pbi, fh, h21o, h22o); }
            else { h12o[0]=h12o[1]=h12o[2]=h12o[3]=0.f;
                   h22o[0]=h22o[1]=h22o[2]=h22o[3]=0.f; }
            #pragma unroll
            for (int k = 0; k < 4; ++k) {
                int j = hc + k;
                float u1x = (j < WW-1) ? ((k < 3) ? v1c[k+1] : v1r) - v1c[k] : 0.f;
                float u2x = (j < WW-1) ? ((k < 3) ? v2c[k+1] : v2r) - v2c[k] : 0.f;
                float u1y = v1d[k] - v1c[k];   // i0-1 < HH-1 always
                float u2y = v2d[k] - v2c[k];
                float d0, d1;
                pupd(0.f, h12o[k], u1x, u1y, taut, d0, h12[k]);
                pupd(0.f, h22o[k], u2x, u2y, taut, d1, h22[k]);
            }
        }
        *(float4*)&sB[0][hc] = pack4h2(h12, h22);
    }
    __syncthreads();

    // ---- Phase 2: u-update ----
    float l11 = 0.f, l21 = 0.f;
    if (tc > 0) {
        float2 lv = __half22float2(sA[tr][tc - 1]);
        l11 = lv.x; l21 = lv.y;
    }
    float4 upv = *(const float4*)&sB[tr][tc];   // (p12,p22)_new at row r-1
    float l12[4], l22[4];
    {
        const __half2* h = (const __half2*)&upv;
        #pragma unroll
        for (int k = 0; k < 4; ++k) {
            float2 v = __half22float2(h[k]);
            l12[k] = v.x; l22[k] = v.y;
        }
    }

    float gx[4], gy[4];
    ld8h(ga, f, gx, gy);
    float4 rc4 = ld4(rc, f);
    const float* rcv = (const float*)&rc4;

    float u1n[4], u2n[4];
    #pragma unroll
    for (int k = 0; k < 4; ++k) {
        int j = tc + k;
        float t11 = (j < WW-1) ? p11n[k] : 0.f;
        float l11k = (k == 0) ? l11 : p11n[k-1];
        float t21 = (j < WW-1) ? p21n[k] : 0.f;
        float l21k = (k == 0) ? l21 : p21n[k-1];
        float t12 = hasDn ? p12n[k] : 0.f;
        float t22 = hasDn ? p22n[k] : 0.f;
        float div1 = (t11 - l11k) + (t12 - l12[k]);
        float div2 = (t21 - l21k) + (t22 - l22[k]);

        float grad = gx[k]*gx[k] + gy[k]*gy[k] + EPSF;
        float rho  = rcv[k] + gx[k]*u1c[k] + gy[k]*u2c[k] + EPSF;
        float v1, v2;
        thresh(gx[k], gy[k], rho, grad, l_t, v1, v2);
        u1n[k] = v1 + u1c[k] + ts * div1;
        u2n[k] = v2 + u2c[k] + ts * div2;
    }

    if (LAST) {
        st4(u1f, f, u1n); st4(u2f, f, u2n);
    } else {
        st8h(upo, f, u1n, u2n);
        st8h(pao, f, p11n, p12n);
        st8h(pbo, f, p21n, p22n);
    }
}

// ---------------------------------------------------------------------------
extern "C" void kernel_launch(void* const* d_in, const int* in_sizes, int n_in,
                              void* d_out, int out_size, void* d_ws, size_t ws_size,
                              hipStream_t stream) {
    const float* x = (const float*)d_in[0];
    const float* y = (const float*)d_in[1];
    const float* t = (const float*)d_in[8];
    const float* l = (const float*)d_in[9];
    const float* a = (const float*)d_in[10];

    float* u1out = (float*)d_out;
    float* u2out = u1out + NPIX;

    // ws: rc(f32) + 7 packed half2 fields = 8 * 16.8 MB = 134 MB
    char* ws = (char*)d_ws;
    float*   rcp_ = (float*)ws;                              ws += (size_t)NPIX * 4;
    __half2* gaP  = (__half2*)ws;                            ws += (size_t)NPIX * 4;
    __half2* upA  = (__half2*)ws;                            ws += (size_t)NPIX * 4;
    __half2* upB  = (__half2*)ws;                            ws += (size_t)NPIX * 4;
    __half2* paA  = (__half2*)ws;                            ws += (size_t)NPIX * 4;
    __half2* pbA  = (__half2*)ws;                            ws += (size_t)NPIX * 4;
    __half2* paB  = (__half2*)ws;                            ws += (size_t)NPIX * 4;
    __half2* pbB  = (__half2*)ws;

    // S: ga, rc, u0 -> upA
    s_kernel<<<dim3(NBLK), dim3(NTHR), 0, stream>>>(x, y, gaP, rcp_, upA, t, l);

    // F1: (p1 from p=0, u1). u: A->B, p: ->A
    f_kernel<true, false><<<dim3(FBLK), dim3(FTHR), 0, stream>>>(
        gaP, rcp_, upA, paA, pbA,     // p_in unused (P0)
        upB, nullptr, nullptr, paA, pbA, t, l, a);

    // F2..F8: u: B->A->B..., p: A->B->A...
    __half2* ups[2] = {upA, upB};
    __half2* pas[2] = {paA, paB};
    __half2* pbs[2] = {pbA, pbB};
    for (int k = 2; k <= 8; ++k) {
        int ui = (k & 1) ? 0 : 1;     // u_in:  k even -> B, k odd -> A
        int pi = (k & 1) ? 1 : 0;     // p_in:  k even -> A, k odd -> B
        f_kernel<false, false><<<dim3(FBLK), dim3(FTHR), 0, stream>>>(
            gaP, rcp_, ups[ui], pas[pi], pbs[pi],
            ups[1 - ui], nullptr, nullptr, pas[1 - pi], pbs[1 - pi], t, l, a);
    }

    // F9: u_in = upA (F8's out), p_in = paB/pbB (F8's out); write fp32 d_out.
    f_kernel<false, true><<<dim3(FBLK), dim3(FTHR), 0, stream>>>(
        gaP, rcp_, upA, paB, pbB,
        nullptr, u1out, u2out, paA, pbA, t, l, a);
}